// Round 8
// baseline (95.863 us; speedup 1.0000x reference)
//
#include <hip/hip_runtime.h>
#include <math.h>
#include <float.h>

#define N_RINGS  10
#define N_ANGLES 36
#define NP       360                  // points per batch
#define PI_APPROX 3.1415926f

#define BLOCK  512        // 8 waves -> 2 blocks/CU (grid 512 = 2/CU)
#define WPB    8
#define CHUNK  1024       // targets per block -> 512 blocks
#define PPT    6          // point-slots per lane: 6*64 = 384 >= 360

typedef float v2f __attribute__((ext_vector_type(2)));

// ---------------- kernel 0: prep ------------------------------------------
// (a) target B x N x 3  ->  pair-SoA quads: per target-pair p:
//     {x0,x1}{y0,y1}{z0,z1}{w0,w1}  (32 B, w = |t|^2). This layout makes
//     wave-uniform scalar loads land as aligned SGPR pairs usable directly
//     as v_pk_fma_f32 sources.
// (b) per-point quads {qx,qy,qz,pp2} with q = -2*p (double-trig here, once,
//     instead of per-block in the hot kernel).
__global__ __launch_bounds__(256) void prep(
    const float* __restrict__ pred,    // B x N_RINGS
    const float* __restrict__ target,  // B x N x 3
    v2f*  __restrict__ tpairs,         // B*(N/2) quads of v2f[4]
    float4* __restrict__ pts4,         // B*NP point quads
    int N, int B)
{
    const int gid = blockIdx.x * blockDim.x + threadIdx.x;
    const int halfN = N >> 1;
    const int pairsTot = B * halfN;

    if (gid < pairsTot) {
        int bp = gid / halfN;
        int pr = gid - bp * halfN;
        const float* t = target + ((size_t)bp * N + 2 * (size_t)pr) * 3;
        float x0 = t[0], y0 = t[1], z0 = t[2];
        float x1 = t[3], y1 = t[4], z1 = t[5];
        v2f* o = tpairs + (size_t)gid * 4;
        o[0] = (v2f){x0, x1};
        o[1] = (v2f){y0, y1};
        o[2] = (v2f){z0, z1};
        o[3] = (v2f){x0 * x0 + y0 * y0 + z0 * z0,
                     x1 * x1 + y1 * y1 + z1 * z1};
    }
    if (gid < B * NP) {
        int bb = gid / NP;
        int p  = gid - bb * NP;
        int j  = p / N_ANGLES;
        int a  = p - j * N_ANGLES;
        float angf = (float)(10 * a) * (2.0f * PI_APPROX / 360.0f);
        double ang = (double)angf;
        float c = (float)cos(ang), s = (float)sin(ang);
        float r  = pred[bb * N_RINGS + j];
        float px = -r * c + 0.04f;
        float py = 0.15f * (float)j - 0.7f;
        float pz = r * s;
        pts4[gid] = make_float4(-2.0f * px, -2.0f * py, -2.0f * pz,
                                px * px + py * py + pz * pz);
    }
}

// ---------------- kernel A: chamfer main ----------------------------------
// No LDS staging. Waves split the chunk's target-pairs; the pair quad is
// read at a wave-uniform address (readfirstlane'd index) from a const
// __restrict__ array -> backend emits s_load_dwordx8 into SGPRs (scalar
// pipe, zero LDS/VMEM-lane traffic). Inner: 3 v_pk_fma_f32 (one SGPR-pair
// src each) + 1 v_min3_f32 per 2 targets per point; loop/address math stays
// on the scalar pipe. Per-wave partial mins combined via tiny LDS; plain
// coalesced partial-row store (kernel boundary = coherence).
__global__ __launch_bounds__(BLOCK) void chamfer_partial(
    const float4* __restrict__ pts4,   // B*NP point quads
    const v2f*  __restrict__ tpairs,   // B*(N/2) pair quads
    float* __restrict__ part,          // B x chunks x NP
    int N, int chunks)
{
    __shared__ float pm[WPB * NP];     // 11.5 KB

    const int b   = blockIdx.x / chunks;
    const int cg  = blockIdx.x % chunks;
    const int tid = threadIdx.x;
    const int lane = tid & 63;
    const int wu  = __builtin_amdgcn_readfirstlane(tid >> 6);  // uniform SGPR

    const int halfN = N >> 1;
    const int pairsChunk = CHUNK >> 1;                 // 512
    const int kend = min(pairsChunk, halfN - cg * pairsChunk);
    const v2f* tpb = tpairs + ((size_t)b * halfN + (size_t)cg * pairsChunk) * 4;

    // per-lane points (prepped quads; coalesced dwordx4 loads)
    float qx[PPT], qy[PPT], qz[PPT], pw[PPT], m[PPT];
    #pragma unroll
    for (int k = 0; k < PPT; ++k) {
        int s  = lane + 64 * k;
        int sc = (s < NP) ? s : (NP - 1);              // dup for dummy slots
        float4 q = pts4[b * NP + sc];
        qx[k] = q.x; qy[k] = q.y; qz[k] = q.z; pw[k] = q.w;
        m[k] = FLT_MAX;
    }

    // main loop: k uniform -> scalar loop, s_load_dwordx8 per pair-quad
    #pragma unroll 4
    for (int k = wu; k < kend; k += WPB) {
        int base = 4 * k;
        v2f xv = tpb[base + 0];
        v2f yv = tpb[base + 1];
        v2f zv = tpb[base + 2];
        v2f wv = tpb[base + 3];
        #pragma unroll
        for (int i = 0; i < PPT; ++i) {
            v2f h = qz[i] * zv + wv;                   // v_pk_fma_f32 (s-pair src)
            h = qy[i] * yv + h;
            h = qx[i] * xv + h;
            m[i] = fminf(m[i], fminf(h.x, h.y));       // v_min3_f32
        }
    }

    // finalize (add pp2, clamp) and publish per-wave partials
    #pragma unroll
    for (int k = 0; k < PPT; ++k) {
        int s = lane + 64 * k;
        if (s < NP) pm[wu * NP + s] = fmaxf(pw[k] + m[k], 0.0f);
    }
    __syncthreads();

    // cross-wave min, coalesced store of this block's partial row
    for (int p = tid; p < NP; p += BLOCK) {
        float v = pm[p];
        #pragma unroll
        for (int ww = 1; ww < WPB; ++ww)
            v = fminf(v, pm[ww * NP + p]);
        part[((size_t)b * chunks + cg) * NP + p] = v;
    }
}

// ---------------- kernel B: one block per batch ---------------------------
__global__ __launch_bounds__(256) void batch_sum(
    const float* __restrict__ part, double* __restrict__ ws2,
    int chunks)
{
    __shared__ double sd[4];
    const int b   = blockIdx.x;
    const int tid = threadIdx.x;
    const float* pb = part + (size_t)b * chunks * NP;

    double s = 0.0;
    for (int p = tid; p < NP; p += 256) {
        float mn = pb[p];
        for (int c = 1; c < chunks; ++c)
            mn = fminf(mn, pb[(size_t)c * NP + p]);
        s += (double)mn;
    }
    #pragma unroll
    for (int off = 32; off > 0; off >>= 1)
        s += __shfl_down(s, off, 64);
    if ((tid & 63) == 0) sd[tid >> 6] = s;
    __syncthreads();
    if (tid == 0)
        ws2[b] = sd[0] + sd[1] + sd[2] + sd[3];
}

// ---------------- kernel C: final mean ------------------------------------
__global__ __launch_bounds__(64) void final_mean(
    const double* __restrict__ ws2, float* __restrict__ out, int B)
{
    const int tid = threadIdx.x;
    double s = (tid < B) ? ws2[tid] : 0.0;
    #pragma unroll
    for (int off = 32; off > 0; off >>= 1)
        s += __shfl_down(s, off, 64);
    if (tid == 0)
        out[0] = (float)(s / (double)(B * NP));
}

extern "C" void kernel_launch(void* const* d_in, const int* in_sizes, int n_in,
                              void* d_out, int out_size, void* d_ws, size_t ws_size,
                              hipStream_t stream) {
    const float* pred   = (const float*)d_in[0];
    const float* target = (const float*)d_in[1];
    // d_in[2] (trans_feat) unused by the reference.

    const int B = in_sizes[0] / N_RINGS;
    const int N = in_sizes[1] / (3 * B);
    const int chunks = (N + CHUNK - 1) / CHUNK;     // 16 for N=16384
    const int halfN  = N >> 1;

    // workspace layout (all offsets 16B-aligned)
    v2f* tpairs = (v2f*)d_ws;                                   // B*halfN*4 v2f
    size_t tpairsBytes = (size_t)B * halfN * 4 * sizeof(v2f);   // 8.39 MB
    float4* pts4 = (float4*)((char*)d_ws + tpairsBytes);        // B*NP quads
    size_t pts4Bytes = (size_t)B * NP * sizeof(float4);         // 184 KB
    float* part = (float*)((char*)d_ws + tpairsBytes + pts4Bytes);
    size_t partBytes = (size_t)B * chunks * NP * sizeof(float); // 737 KB
    double* ws2 = (double*)((char*)d_ws + tpairsBytes + pts4Bytes + partBytes);
    float* out = (float*)d_out;

    const int prepThreads = B * halfN;              // >= B*NP
    hipLaunchKernelGGL(prep, dim3((prepThreads + 255) / 256), dim3(256), 0, stream,
                       pred, target, tpairs, pts4, N, B);
    hipLaunchKernelGGL(chamfer_partial, dim3(B * chunks), dim3(BLOCK), 0, stream,
                       pts4, tpairs, part, N, chunks);
    hipLaunchKernelGGL(batch_sum, dim3(B), dim3(256), 0, stream,
                       part, ws2, chunks);
    hipLaunchKernelGGL(final_mean, dim3(1), dim3(64), 0, stream,
                       ws2, out, B);
}